// Round 2
// baseline (353.214 us; speedup 1.0000x reference)
//
#include <hip/hip_runtime.h>
#include <climits>

#define N_MASKS 64
#define H 1024
#define W 1024
#define ROWS_PER_BLOCK 16
#define BLOCKS_PER_MASK (H / ROWS_PER_BLOCK)  // 64
#define THREADS 256

__device__ __forceinline__ int imin(int a, int b) { return a < b ? a : b; }
__device__ __forceinline__ int imax(int a, int b) { return a > b ? a : b; }

// Phase 1: one block per (mask, 16-row slab). 256 threads cover one full row per
// load step (256 * uint4 = 4 KB = 1024 floats). Loads are issued 8-at-a-time into
// registers before any processing so 8 dwordx4 stay in flight per thread (L3-latency
// hiding). Active-pixel test is an integer compare against 0x3F800000 (1.0f), packed
// into a 4-bit mask consumed by popc/ffs/clz. Every ws slot is unconditionally
// written each launch, so the harness 0xAA poison is harmless.
__global__ __launch_bounds__(THREADS) void fastsam_partial(
    const float* __restrict__ masks, int* __restrict__ ws) {
    const int mask = blockIdx.y;
    const int bx = blockIdx.x;
    const int r0 = bx * ROWS_PER_BLOCK;
    const int t = threadIdx.x;
    const unsigned ONE = 0x3F800000u;  // bit pattern of 1.0f

    const uint4* base = (const uint4*)(masks + (size_t)mask * H * W);
    const int col = t * 4;  // thread t covers cols [4t, 4t+3] of every row

    int cmin = INT_MAX, rmin = INT_MAX, cmax = -1, rmax = -1, cnt = 0;

#pragma unroll
    for (int half = 0; half < 2; ++half) {
        const int rbase = r0 + half * 8;
        uint4 v[8];
#pragma unroll
        for (int i = 0; i < 8; ++i) v[i] = base[(rbase + i) * (W / 4) + t];
#pragma unroll
        for (int i = 0; i < 8; ++i) {
            int bits = (int)(v[i].x == ONE) | ((int)(v[i].y == ONE) << 1) |
                       ((int)(v[i].z == ONE) << 2) | ((int)(v[i].w == ONE) << 3);
            cnt += __popc(bits);
            if (bits) {
                const int row = rbase + i;
                rmin = imin(rmin, row);
                rmax = row;  // rows visited in ascending order
                cmin = imin(cmin, col + __ffs(bits) - 1);
                cmax = imax(cmax, col + 31 - __clz(bits));
            }
        }
    }

    // wave-64 butterfly reduce
#pragma unroll
    for (int off = 32; off > 0; off >>= 1) {
        cmin = imin(cmin, __shfl_down(cmin, off));
        rmin = imin(rmin, __shfl_down(rmin, off));
        cmax = imax(cmax, __shfl_down(cmax, off));
        rmax = imax(rmax, __shfl_down(rmax, off));
        cnt += __shfl_down(cnt, off);
    }

    __shared__ int s[4][5];
    const int wave = t >> 6;
    const int lane = t & 63;
    if (lane == 0) {
        s[wave][0] = cmin;
        s[wave][1] = rmin;
        s[wave][2] = cmax;
        s[wave][3] = rmax;
        s[wave][4] = cnt;
    }
    __syncthreads();
    if (t == 0) {
#pragma unroll
        for (int wv = 1; wv < 4; ++wv) {
            cmin = imin(cmin, s[wv][0]);
            rmin = imin(rmin, s[wv][1]);
            cmax = imax(cmax, s[wv][2]);
            rmax = imax(rmax, s[wv][3]);
            cnt += s[wv][4];
        }
        int* p = ws + (size_t)(mask * BLOCKS_PER_MASK + bx) * 5;
        p[0] = cmin;
        p[1] = rmin;
        p[2] = cmax;
        p[3] = rmax;
        p[4] = cnt;
    }
}

// Phase 2: one single-wave block per mask; 64 lanes each grab one partial,
// butterfly-reduce, apply the area test, write the bbox as one float4.
__global__ __launch_bounds__(64) void fastsam_final(
    const int* __restrict__ ws, float* __restrict__ out) {
    const int mask = blockIdx.x;
    const int j = threadIdx.x;  // 0..63, one wave

    const int* p = ws + (size_t)(mask * BLOCKS_PER_MASK + j) * 5;
    int cmin = p[0], rmin = p[1], cmax = p[2], rmax = p[3], cnt = p[4];

#pragma unroll
    for (int off = 32; off > 0; off >>= 1) {
        cmin = imin(cmin, __shfl_down(cmin, off));
        rmin = imin(rmin, __shfl_down(rmin, off));
        cmax = imax(cmax, __shfl_down(cmax, off));
        rmax = imax(rmax, __shfl_down(rmax, off));
        cnt += __shfl_down(cnt, off);
    }
    if (j == 0) {
        // area_thresh = (1024/32)*(1024/32) = 1024; binary mask => sum == count
        const bool keep = cnt > 1024;
        float4 bbox = keep ? make_float4((float)cmin, (float)rmin, (float)cmax, (float)rmax)
                           : make_float4(0.0f, 0.0f, 0.0f, 0.0f);
        *(float4*)(out + mask * 4) = bbox;
    }
}

extern "C" void kernel_launch(void* const* d_in, const int* in_sizes, int n_in,
                              void* d_out, int out_size, void* d_ws, size_t ws_size,
                              hipStream_t stream) {
    const float* masks = (const float*)d_in[0];
    float* out = (float*)d_out;
    int* ws = (int*)d_ws;

    dim3 grid(BLOCKS_PER_MASK, N_MASKS);  // 64 x 64 = 4096 blocks
    fastsam_partial<<<grid, THREADS, 0, stream>>>(masks, ws);
    fastsam_final<<<N_MASKS, 64, 0, stream>>>(ws, out);
}